// Round 11
// baseline (1812.348 us; speedup 1.0000x reference)
//
#include <hip/hip_runtime.h>
#include <hip/hip_bf16.h>
#include <math.h>

#define B_ 32
#define N_ 256
#define DIM_ 384
#define H_ 6
#define DH_ 64
#define INNER_ 384
#define MLP_ 1536
#define DEPTH_ 12
#define T_ (B_ * N_)   // 8192 tokens

typedef __bf16 bf16x8 __attribute__((ext_vector_type(8)));
typedef __bf16 bf16x4 __attribute__((ext_vector_type(4)));
typedef float f32x4 __attribute__((ext_vector_type(4)));

typedef const __attribute__((address_space(1))) void* gas_ptr;
typedef __attribute__((address_space(3))) void* las_ptr;

// wbuf layout (bf16, per layer, transposed [n][k])
#define WQKV_OFF 0                      // [1152][384]
#define WO_OFF   (1152 * 384)           // [384][384]
#define W1_OFF   (WO_OFF + 384 * 384)   // [1536][384]
#define W2_OFF   (W1_OFF + 1536 * 384)  // [384][1536]
#define WBUF_ELEMS (W2_OFF + 384 * 1536)

// ---------------- weight pre-pack, ALL layers in one dispatch ----------------
__global__ __launch_bounds__(256) void convert_w_all(
    const float* __restrict__ wq0, const float* __restrict__ wkv0,
    const float* __restrict__ wo0, const float* __restrict__ w10,
    const float* __restrict__ w20, __bf16* __restrict__ wbuf0)
{
    __shared__ float til[64][65];
    int t = blockIdx.x;
    int l = t / 432; t -= l * 432;
    const float* wq  = wq0  + (size_t)l * DIM_ * INNER_;
    const float* wkv = wkv0 + (size_t)l * DIM_ * 2 * INNER_;
    const float* wo  = wo0  + (size_t)l * INNER_ * DIM_;
    const float* w1  = w10  + (size_t)l * DIM_ * MLP_;
    const float* w2  = w20  + (size_t)l * MLP_ * DIM_;
    __bf16* wbuf = wbuf0 + (size_t)l * WBUF_ELEMS;

    int lane = threadIdx.x & 63, seg = threadIdx.x >> 6;
    const float* src; __bf16* dst;
    int Ns, sc, dK, dR, k0;
    if (t < 108) {                      // wqkv_t [1152][384]
        int nt = t / 6, kt = t % 6;
        int n0 = nt * 64; k0 = kt * 64;
        dst = wbuf + WQKV_OFF; dK = 384; dR = n0;
        if (n0 < 384) { src = wq;  Ns = 384; sc = n0; }
        else          { src = wkv; Ns = 768; sc = n0 - 384; }
    } else if (t < 144) {               // wo_t [384][384]
        int u = t - 108; int nt = u / 6, kt = u % 6;
        src = wo; Ns = 384; sc = nt * 64;
        dst = wbuf + WO_OFF; dK = 384; dR = nt * 64; k0 = kt * 64;
    } else if (t < 288) {               // w1_t [1536][384]
        int u = t - 144; int nt = u / 6, kt = u % 6;
        src = w1; Ns = 1536; sc = nt * 64;
        dst = wbuf + W1_OFF; dK = 384; dR = nt * 64; k0 = kt * 64;
    } else {                            // w2_t [384][1536]
        int u = t - 288; int nt = u / 24, kt = u % 24;
        src = w2; Ns = 384; sc = nt * 64;
        dst = wbuf + W2_OFF; dK = 1536; dR = nt * 64; k0 = kt * 64;
    }
    #pragma unroll
    for (int r = 0; r < 16; ++r) {
        int i = seg * 16 + r;
        til[i][lane] = src[(size_t)(k0 + i) * Ns + sc + lane];
    }
    __syncthreads();
    #pragma unroll
    for (int r = 0; r < 16; ++r) {
        int i = seg * 16 + r;
        dst[(size_t)(dR + i) * dK + k0 + lane] = (__bf16)til[lane][i];
    }
}

// ---------------- layernorm: wave per token, 4 tokens per block ----------
__global__ __launch_bounds__(256) void ln1w(
    const float* __restrict__ x, const float* __restrict__ g,
    const float* __restrict__ b, __bf16* __restrict__ y)
{
    size_t row = blockIdx.x * 4 + (threadIdx.x >> 6);
    int lane = threadIdx.x & 63;
    const float* xr = x + row * DIM_;
    float v[6];
    #pragma unroll
    for (int s = 0; s < 6; ++s) v[s] = xr[lane + 64 * s];
    float sum = 0.f;
    #pragma unroll
    for (int s = 0; s < 6; ++s) sum += v[s];
    #pragma unroll
    for (int o = 32; o > 0; o >>= 1) sum += __shfl_xor(sum, o);
    float mu = sum * (1.0f / DIM_);
    float var = 0.f;
    #pragma unroll
    for (int s = 0; s < 6; ++s) { float d = v[s] - mu; var += d * d; }
    #pragma unroll
    for (int o = 32; o > 0; o >>= 1) var += __shfl_xor(var, o);
    float rs = rsqrtf(var * (1.0f / DIM_) + 1e-5f);
    __bf16* yr = y + row * DIM_;
    #pragma unroll
    for (int s = 0; s < 6; ++s) {
        int e = lane + 64 * s;
        yr[e] = (__bf16)((v[s] - mu) * rs * g[e] + b[e]);
    }
}

// ---------------- m97-structure MFMA GEMM + counted-vmcnt pipeline ----------
// STREAMB=false: A + B staged via global_load_lds DMA (R4-verified path).
// STREAMB=true  (BK=32, 128x128 only): A staged via DMA/LDS as before; B fragments
//   streamed from L2 directly into a double-buffered REGISTER set (same gather
//   pattern as attn's V reads). Halves LDS traffic + staging DMA in the
//   LDS-BW-bound regime; LDS drops to 16 KB. vmcnt ledger: 2 A-DMA + 4 B-loads
//   in flight -> vmcnt(6) steady-state.
// Block order: bn fastest within an XCD chunk -> A-panel + B weights L2-resident.
// BK=64 path uses rule-21 swizzle pair.
template<int MODE, int K, int BM, int BN, int BK, int NT, bool STREAMB = false>
__global__ __launch_bounds__(256) void gemmt(
    const __bf16* __restrict__ A, const __bf16* __restrict__ Bt,
    const float* __restrict__ bias, const float* __restrict__ ls,
    float* __restrict__ xf, __bf16* __restrict__ out,
    __bf16* __restrict__ oq, __bf16* __restrict__ ok, __bf16* __restrict__ ov,
    int Nn)
{
    constexpr int WM = BM / 32, WN = BN / 32;
    constexpr int KS = BK / 32;
    constexpr int MT = T_ / BM;
    constexpr int nIter = K / BK;
    constexpr bool SWZ = (BK == 64);
    constexpr int RPI = 512 / BK;                 // rows per stage instr (1 KB each)
    constexpr int CL  = BK / 8;                   // 16B col slots per row
    static_assert(!STREAMB || (BK == 32 && BM == 128 && BN == 128), "STREAMB mapping");

    __shared__ __align__(16) __bf16 sA[2][BM * BK];
    __shared__ __align__(16) __bf16 sB[STREAMB ? 1 : 2][STREAMB ? 16 : BN * BK];

    int id = blockIdx.x;
    constexpr int nxg = (MT * NT) / 8;
    int wg = (id & 7) * nxg + (id >> 3);          // bijective XCD-chunked swizzle
    int bm = (wg / NT) * BM;                      // bm SLOW within XCD chunk
    int bn = (wg % NT) * BN;                      // bn fast -> panel reuse in L2
    int tid = threadIdx.x;
    int lane = tid & 63, wid = tid >> 6;
    int wm = (wid & 1) * (BM / 2), wn = (wid >> 1) * (BN / 2);
    int fm = lane & 15, fq = lane >> 4;

    f32x4 acc[WM][WN] = {};

    int lr = lane / CL, lc = lane % CL;
    int lcs = SWZ ? (lc ^ lr) : lc;               // pre-swizzled source col slot
    const __bf16* aBase = A + (size_t)(bm + wid * RPI + lr) * K + lcs * 8;
    const __bf16* bBase = Bt + (size_t)(bn + wid * RPI + lr) * K + lcs * 8;

    auto stageA = [&](int buf, int kk) {
        #pragma unroll
        for (int qI = 0; qI < BM / (4 * RPI); ++qI)
            __builtin_amdgcn_global_load_lds(
                (gas_ptr)(aBase + (size_t)(qI * 4 * RPI) * K + kk),
                (las_ptr)&sA[buf][qI * 2048 + wid * 512], 16, 0, 0);
    };
    auto stageB = [&](int buf, int kk) {
        if constexpr (!STREAMB) {
            #pragma unroll
            for (int qI = 0; qI < BN / (4 * RPI); ++qI)
                __builtin_amdgcn_global_load_lds(
                    (gas_ptr)(bBase + (size_t)(qI * 4 * RPI) * K + kk),
                    (las_ptr)&sB[buf][qI * 2048 + wid * 512], 16, 0, 0);
        }
    };

    if constexpr (STREAMB) {
        // ---- B in registers, double-buffered; A via verified DMA/LDS pipeline ----
        const __bf16* bFrag = Bt + (size_t)(bn + wn + fm) * K + fq * 8;
        bf16x8 breg[2][WN];
        auto loadB = [&](int set, int kk) {
            #pragma unroll
            for (int jj = 0; jj < WN; ++jj)
                breg[set][jj] = *(const bf16x8*)(bFrag + (size_t)(jj * 16) * K + kk);
        };

        stageA(0, 0); loadB(0, 0);   // 2 DMA + 4 loads in flight

        #pragma unroll
        for (int i = 0; i < nIter; ++i) {
            int cur = i & 1;
            if (i + 1 < nIter) {
                stageA(cur ^ 1, (i + 1) * BK);
                loadB(cur ^ 1, (i + 1) * BK);
                asm volatile("s_waitcnt vmcnt(6)" ::: "memory");  // A(i)+B(i) done
            } else {
                asm volatile("s_waitcnt vmcnt(0)" ::: "memory");
            }
            __builtin_amdgcn_s_barrier();
            __builtin_amdgcn_sched_barrier(0);

            bf16x8 af[WM];
            #pragma unroll
            for (int ii = 0; ii < WM; ++ii)
                af[ii] = *(const bf16x8*)&sA[cur][(wm + ii * 16 + fm) * BK + fq * 8];
            #pragma unroll
            for (int ii = 0; ii < WM; ++ii)
                #pragma unroll
                for (int jj = 0; jj < WN; ++jj)
                    acc[ii][jj] = __builtin_amdgcn_mfma_f32_16x16x32_bf16(
                        af[ii], breg[cur][jj], acc[ii][jj], 0, 0, 0);

            if (i + 1 < nIter) {
                asm volatile("s_waitcnt lgkmcnt(0)" ::: "memory");
                __builtin_amdgcn_sched_barrier(0);
                __builtin_amdgcn_s_barrier();
                __builtin_amdgcn_sched_barrier(0);
            }
        }
    } else {
        // ---- R4-verified DMA A+B path ----
        constexpr int LPT = BM / (4 * RPI) + BN / (4 * RPI);
        static_assert(LPT == 4, "vmcnt literal assumes 4 loads per tile per wave");
        stageA(0, 0); stageB(0, 0);

        #pragma unroll
        for (int i = 0; i < nIter; ++i) {
            int cur = i & 1;
            if (i + 1 < nIter) {
                stageA(cur ^ 1, (i + 1) * BK);
                stageB(cur ^ 1, (i + 1) * BK);
                asm volatile("s_waitcnt vmcnt(4)" ::: "memory");   // tile i resident
            } else {
                asm volatile("s_waitcnt vmcnt(0)" ::: "memory");
            }
            __builtin_amdgcn_s_barrier();
            __builtin_amdgcn_sched_barrier(0);

            bf16x8 af[KS][WM], bfr[KS][WN];
            #pragma unroll
            for (int ks = 0; ks < KS; ++ks) {
                #pragma unroll
                for (int ii = 0; ii < WM; ++ii) {
                    int row = wm + ii * 16 + fm;
                    int c = SWZ ? (((ks * 4 + fq) ^ (row & 7)) * 8) : (ks * 32 + fq * 8);
                    af[ks][ii] = *(const bf16x8*)&sA[cur][row * BK + c];
                }
                #pragma unroll
                for (int jj = 0; jj < WN; ++jj) {
                    int row = wn + jj * 16 + fm;
                    int c = SWZ ? (((ks * 4 + fq) ^ (row & 7)) * 8) : (ks * 32 + fq * 8);
                    bfr[ks][jj] = *(const bf16x8*)&sB[cur][row * BK + c];
                }
            }
            #pragma unroll
            for (int ks = 0; ks < KS; ++ks)
                #pragma unroll
                for (int ii = 0; ii < WM; ++ii)
                    #pragma unroll
                    for (int jj = 0; jj < WN; ++jj)
                        acc[ii][jj] = __builtin_amdgcn_mfma_f32_16x16x32_bf16(
                            af[ks][ii], bfr[ks][jj], acc[ii][jj], 0, 0, 0);

            if (i + 1 < nIter) {
                asm volatile("s_waitcnt lgkmcnt(0)" ::: "memory");
                __builtin_amdgcn_sched_barrier(0);
                __builtin_amdgcn_s_barrier();
                __builtin_amdgcn_sched_barrier(0);
            }
        }
    }

    // epilogue: C/D layout col=lane&15, row=(lane>>4)*4+reg
    #pragma unroll
    for (int jj = 0; jj < WN; ++jj) {
        int col = bn + wn + jj * 16 + fm;
        float bv = (MODE != 0) ? bias[col] : 0.0f;
        float lv = (MODE == 2) ? ls[col] : 0.0f;
        #pragma unroll
        for (int ii = 0; ii < WM; ++ii) {
            #pragma unroll
            for (int r = 0; r < 4; ++r) {
                int row = bm + wm + ii * 16 + fq * 4 + r;
                float v = acc[ii][jj][r];
                if (MODE == 0) {
                    if (col < 384)      oq[(size_t)row * 384 + col] = (__bf16)v;
                    else if (col < 768) ok[(size_t)row * 384 + col - 384] = (__bf16)v;
                    else {
                        int bb = row >> 8, tj = row & 255;
                        ov[((size_t)bb * 384 + (col - 768)) * 256 + tj] = (__bf16)v;
                    }
                } else if (MODE == 1) {
                    v += bv;
                    v = 0.5f * v * (1.0f + erff(v * 0.70710678118f));
                    out[(size_t)row * Nn + col] = (__bf16)v;
                } else {
                    size_t idx = (size_t)row * Nn + col;
                    xf[idx] = (v + bv) * lv + xf[idx];
                }
            }
        }
    }
}

// ---------------- fused MFMA talking-heads attention (v3, verified R4 config) ----------------
#define PAD_S 264

__global__ __launch_bounds__(384) void attn_mfma(
    const __bf16* __restrict__ q, const __bf16* __restrict__ kb,
    const __bf16* __restrict__ vT, const float* __restrict__ scale,
    const float* __restrict__ mp, const float* __restrict__ mq,
    __bf16* __restrict__ o)
{
    __shared__ __bf16 sbuf[96][PAD_S];

    int id = blockIdx.x;
    int b = (id & 7) + ((id >> 3) & 3) * 8;
    int i0 = (id >> 5) * 16;
    int tid = threadIdx.x;
    int lane = tid & 63, wid = tid >> 6;
    int fm = lane & 15, fq = lane >> 4;

    // ---- Phase 1 — QK^T: wave h computes raw S_h[16][256] ----
    int h = wid;
    bf16x8 qf[2];
    #pragma unroll
    for (int ks = 0; ks < 2; ++ks)
        qf[ks] = *(const bf16x8*)&q[(size_t)(b * 256 + i0 + fm) * 384 + h * 64 + ks * 32 + fq * 8];
    #pragma unroll 4
    for (int jt = 0; jt < 16; ++jt) {
        f32x4 a = {};
        #pragma unroll
        for (int ks = 0; ks < 2; ++ks) {
            bf16x8 bfr = *(const bf16x8*)&kb[(size_t)(b * 256 + jt * 16 + fm) * 384 + h * 64 + ks * 32 + fq * 8];
            a = __builtin_amdgcn_mfma_f32_16x16x32_bf16(qf[ks], bfr, a, 0, 0, 0);
        }
        #pragma unroll
        for (int r = 0; r < 4; ++r)
            sbuf[h * 16 + fq * 4 + r][jt * 16 + fm] = (__bf16)a[r];
    }

    float mps[36], mqs[36];
    #pragma unroll
    for (int t = 0; t < 36; ++t) { mps[t] = mp[t] * scale[t / 6]; mqs[t] = mq[t]; }

    __syncthreads();

    // ---- Phase 2 — fused premix + mask + softmax + postmix, wave per row ----
    for (int i = wid; i < 16; i += 6) {
        float sv[6][4];
        #pragma unroll
        for (int h2 = 0; h2 < 6; ++h2) {
            bf16x4 v4 = *(const bf16x4*)&sbuf[h2 * 16 + i][lane * 4];
            #pragma unroll
            for (int c = 0; c < 4; ++c) sv[h2][c] = (float)v4[c];
        }
        int drow = i0 + i;
        float pv[6][4];
        #pragma unroll
        for (int g2 = 0; g2 < 6; ++g2) {
            float t0[4];
            #pragma unroll
            for (int c = 0; c < 4; ++c) {
                float r2 = 0.f;
                #pragma unroll
                for (int h2 = 0; h2 < 6; ++h2) r2 += sv[h2][c] * mps[h2 * 6 + g2];
                t0[c] = (lane * 4 + c == drow) ? -1e30f : r2;
            }
            float m = fmaxf(fmaxf(t0[0], t0[1]), fmaxf(t0[2], t0[3]));
            #pragma unroll
            for (int off = 32; off > 0; off >>= 1) m = fmaxf(m, __shfl_xor(m, off));
            float e0 = __expf(t0[0] - m), e1 = __expf(t0[1] - m);
            float e2 = __expf(t0[2] - m), e3 = __expf(t0[3] - m);
            float s = e0 + e1 + e2 + e3;
            #pragma unroll
            for (int off = 32; off > 0; off >>= 1) s += __shfl_xor(s, off);
            float inv = 1.0f / s;
            pv[g2][0] = e0 * inv; pv[g2][1] = e1 * inv;
            pv[g2][2] = e2 * inv; pv[g2][3] = e3 * inv;
        }
        #pragma unroll
        for (int g2 = 0; g2 < 6; ++g2) {
            bf16x4 w4;
            #pragma unroll
            for (int c = 0; c < 4; ++c) {
                float r2 = 0.f;
                #pragma unroll
                for (int h2 = 0; h2 < 6; ++h2) r2 += pv[h2][c] * mqs[h2 * 6 + g2];
                w4[c] = (__bf16)r2;
            }
            *(bf16x4*)&sbuf[g2 * 16 + i][lane * 4] = w4;
        }
    }
    __syncthreads();

    // ---- Phase 3 — P @ V ----
    int gg = wid;
    f32x4 acco[4] = {};
    #pragma unroll
    for (int jc = 0; jc < 4; ++jc) {
        #pragma unroll
        for (int ks = 0; ks < 2; ++ks) {
            bf16x8 af = *(const bf16x8*)&sbuf[gg * 16 + fm][jc * 64 + ks * 32 + fq * 8];
            #pragma unroll
            for (int nt = 0; nt < 4; ++nt) {
                bf16x8 bfr = *(const bf16x8*)&vT[(size_t)(b * 384 + gg * 64 + nt * 16 + fm) * 256 + jc * 64 + ks * 32 + fq * 8];
                acco[nt] = __builtin_amdgcn_mfma_f32_16x16x32_bf16(af, bfr, acco[nt], 0, 0, 0);
            }
        }
    }
    #pragma unroll
    for (int nt = 0; nt < 4; ++nt)
        #pragma unroll
        for (int r = 0; r < 4; ++r)
            o[(size_t)(b * 256 + i0 + fq * 4 + r) * 384 + gg * 64 + nt * 16 + fm] = (__bf16)acco[nt][r];
}

extern "C" void kernel_launch(void* const* d_in, const int* in_sizes, int n_in,
                              void* d_out, int out_size, void* d_ws, size_t ws_size,
                              hipStream_t stream) {
    const float* x      = (const float*)d_in[0];
    const float* ln1_g  = (const float*)d_in[1];
    const float* ln1_b  = (const float*)d_in[2];
    const float* wq     = (const float*)d_in[3];
    const float* wkv    = (const float*)d_in[4];
    const float* scale  = (const float*)d_in[5];
    const float* mixp   = (const float*)d_in[6];
    const float* mixq   = (const float*)d_in[7];
    const float* wo     = (const float*)d_in[8];
    const float* bo     = (const float*)d_in[9];
    const float* ls1    = (const float*)d_in[10];
    const float* ln2_g  = (const float*)d_in[11];
    const float* ln2_b  = (const float*)d_in[12];
    const float* w1     = (const float*)d_in[13];
    const float* b1     = (const float*)d_in[14];
    const float* w2     = (const float*)d_in[15];
    const float* b2     = (const float*)d_in[16];
    const float* ls2    = (const float*)d_in[17];

    char* ws = (char*)d_ws;
    float*  xf = (float*)ws;                      ws += (size_t)T_ * DIM_ * 4;
    __bf16* y  = (__bf16*)ws;                     ws += (size_t)T_ * DIM_ * 2;
    __bf16* q  = (__bf16*)ws;                     ws += (size_t)T_ * DIM_ * 2;
    __bf16* kb = (__bf16*)ws;                     ws += (size_t)T_ * DIM_ * 2;
    __bf16* vT = (__bf16*)ws;                     ws += (size_t)T_ * DIM_ * 2;
    __bf16* o  = (__bf16*)ws;                     ws += (size_t)T_ * DIM_ * 2;
    __bf16* wbuf = (__bf16*)ws;                   ws += (size_t)WBUF_ELEMS * DEPTH_ * 2;
    __bf16* h  = q;   // MLP hidden [T][1536] overlays q+kb+vT+o (25.2MB, exact fit)

    size_t nBytes = (size_t)T_ * DIM_ * sizeof(float);
    hipMemcpyAsync(xf, x, nBytes, hipMemcpyDeviceToDevice, stream);

    // all-layer weight conversion up front (one dispatch)
    convert_w_all<<<432 * DEPTH_, 256, 0, stream>>>(wq, wkv, wo, w1, w2, wbuf);

    for (int l = 0; l < DEPTH_; ++l) {
        __bf16* wl = wbuf + (size_t)l * WBUF_ELEMS;

        ln1w<<<T_ / 4, 256, 0, stream>>>(xf, ln1_g + (size_t)l * DIM_, ln1_b + (size_t)l * DIM_, y);

        // QKV: 576 blocks (128x128, STREAMB: B from L2 into regs)
        gemmt<0, 384, 128, 128, 32, 9, true><<<576, 256, 0, stream>>>(
            y, wl + WQKV_OFF, nullptr, nullptr, nullptr, nullptr,
            q, kb, vT, 1152);

        // attention: 512 blocks, batch pinned to XCD
        attn_mfma<<<512, 384, 0, stream>>>(
            q, kb, vT, scale + (size_t)l * H_,
            mixp + (size_t)l * H_ * H_, mixq + (size_t)l * H_ * H_, o);

        // O-proj: 768 blocks (64x64, BK=64 swizzled, verified DMA path)
        gemmt<2, 384, 64, 64, 64, 6><<<768, 256, 0, stream>>>(
            o, wl + WO_OFF, bo + (size_t)l * DIM_, ls1 + (size_t)l * DIM_,
            xf, nullptr, nullptr, nullptr, nullptr, DIM_);

        ln1w<<<T_ / 4, 256, 0, stream>>>(xf, ln2_g + (size_t)l * DIM_, ln2_b + (size_t)l * DIM_, y);

        // MLP1: 768 blocks (128x128, STREAMB)
        gemmt<1, 384, 128, 128, 32, 12, true><<<768, 256, 0, stream>>>(
            y, wl + W1_OFF, b1 + (size_t)l * MLP_, nullptr,
            nullptr, h, nullptr, nullptr, nullptr, MLP_);

        // MLP2: 768 blocks (64x64, BK=64 swizzled, K=1536, verified DMA path)
        gemmt<2, 1536, 64, 64, 64, 6><<<768, 256, 0, stream>>>(
            h, wl + W2_OFF, b2 + (size_t)l * DIM_, ls2 + (size_t)l * DIM_,
            xf, nullptr, nullptr, nullptr, nullptr, DIM_);
    }

    hipMemcpyAsync(d_out, xf, nBytes, hipMemcpyDeviceToDevice, stream);
}

// Round 12
// 1627.964 us; speedup vs baseline: 1.1133x; 1.1133x over previous
//
#include <hip/hip_runtime.h>
#include <hip/hip_bf16.h>
#include <math.h>

#define B_ 32
#define N_ 256
#define DIM_ 384
#define H_ 6
#define DH_ 64
#define INNER_ 384
#define MLP_ 1536
#define DEPTH_ 12
#define T_ (B_ * N_)   // 8192 tokens

typedef __bf16 bf16x8 __attribute__((ext_vector_type(8)));
typedef __bf16 bf16x4 __attribute__((ext_vector_type(4)));
typedef float f32x4 __attribute__((ext_vector_type(4)));

typedef const __attribute__((address_space(1))) void* gas_ptr;
typedef __attribute__((address_space(3))) void* las_ptr;

// wbuf layout (bf16, per layer, transposed [n][k])
#define WQKV_OFF 0                      // [1152][384]
#define WO_OFF   (1152 * 384)           // [384][384]
#define W1_OFF   (WO_OFF + 384 * 384)   // [1536][384]
#define W2_OFF   (W1_OFF + 1536 * 384)  // [384][1536]
#define WBUF_ELEMS (W2_OFF + 384 * 1536)

// ---------------- weight pre-pack, ALL layers in one dispatch ----------------
__global__ __launch_bounds__(256) void convert_w_all(
    const float* __restrict__ wq0, const float* __restrict__ wkv0,
    const float* __restrict__ wo0, const float* __restrict__ w10,
    const float* __restrict__ w20, __bf16* __restrict__ wbuf0)
{
    __shared__ float til[64][65];
    int t = blockIdx.x;
    int l = t / 432; t -= l * 432;
    const float* wq  = wq0  + (size_t)l * DIM_ * INNER_;
    const float* wkv = wkv0 + (size_t)l * DIM_ * 2 * INNER_;
    const float* wo  = wo0  + (size_t)l * INNER_ * DIM_;
    const float* w1  = w10  + (size_t)l * DIM_ * MLP_;
    const float* w2  = w20  + (size_t)l * MLP_ * DIM_;
    __bf16* wbuf = wbuf0 + (size_t)l * WBUF_ELEMS;

    int lane = threadIdx.x & 63, seg = threadIdx.x >> 6;
    const float* src; __bf16* dst;
    int Ns, sc, dK, dR, k0;
    if (t < 108) {                      // wqkv_t [1152][384]
        int nt = t / 6, kt = t % 6;
        int n0 = nt * 64; k0 = kt * 64;
        dst = wbuf + WQKV_OFF; dK = 384; dR = n0;
        if (n0 < 384) { src = wq;  Ns = 384; sc = n0; }
        else          { src = wkv; Ns = 768; sc = n0 - 384; }
    } else if (t < 144) {               // wo_t [384][384]
        int u = t - 108; int nt = u / 6, kt = u % 6;
        src = wo; Ns = 384; sc = nt * 64;
        dst = wbuf + WO_OFF; dK = 384; dR = nt * 64; k0 = kt * 64;
    } else if (t < 288) {               // w1_t [1536][384]
        int u = t - 144; int nt = u / 6, kt = u % 6;
        src = w1; Ns = 1536; sc = nt * 64;
        dst = wbuf + W1_OFF; dK = 384; dR = nt * 64; k0 = kt * 64;
    } else {                            // w2_t [384][1536]
        int u = t - 288; int nt = u / 24, kt = u % 24;
        src = w2; Ns = 384; sc = nt * 64;
        dst = wbuf + W2_OFF; dK = 1536; dR = nt * 64; k0 = kt * 64;
    }
    #pragma unroll
    for (int r = 0; r < 16; ++r) {
        int i = seg * 16 + r;
        til[i][lane] = src[(size_t)(k0 + i) * Ns + sc + lane];
    }
    __syncthreads();
    #pragma unroll
    for (int r = 0; r < 16; ++r) {
        int i = seg * 16 + r;
        dst[(size_t)(dR + i) * dK + k0 + lane] = (__bf16)til[lane][i];
    }
}

// ---------------- layernorm: one WAVE per token; fp32 in, bf16 out ----------
__global__ __launch_bounds__(64) void ln1w(
    const float* __restrict__ x, const float* __restrict__ g,
    const float* __restrict__ b, __bf16* __restrict__ y)
{
    size_t row = blockIdx.x;
    int lane = threadIdx.x;
    const float* xr = x + row * DIM_;
    float v[6];
    #pragma unroll
    for (int s = 0; s < 6; ++s) v[s] = xr[lane + 64 * s];
    float sum = 0.f;
    #pragma unroll
    for (int s = 0; s < 6; ++s) sum += v[s];
    #pragma unroll
    for (int o = 32; o > 0; o >>= 1) sum += __shfl_xor(sum, o);
    float mu = sum * (1.0f / DIM_);
    float var = 0.f;
    #pragma unroll
    for (int s = 0; s < 6; ++s) { float d = v[s] - mu; var += d * d; }
    #pragma unroll
    for (int o = 32; o > 0; o >>= 1) var += __shfl_xor(var, o);
    float rs = rsqrtf(var * (1.0f / DIM_) + 1e-5f);
    __bf16* yr = y + row * DIM_;
    #pragma unroll
    for (int s = 0; s < 6; ++s) {
        int e = lane + 64 * s;
        yr[e] = (__bf16)((v[s] - mu) * rs * g[e] + b[e]);
    }
}

// ---------------- m97-structure MFMA GEMM + counted-vmcnt pipeline (R4, best verified) ----
// Double-buffered LDS. Per K-step: stage(next) -> vmcnt(4) [current resident, next in
// flight across barrier] -> s_barrier -> ds_read+MFMA -> lgkmcnt(0) -> s_barrier.
// Block order: bn fastest within an XCD chunk -> A-panel L2-resident per XCD.
// BK=64 path uses rule-21 swizzle pair.
template<int MODE, int K, int BM, int BN, int BK, int NT>
__global__ __launch_bounds__(256) void gemmt(
    const __bf16* __restrict__ A, const __bf16* __restrict__ Bt,
    const float* __restrict__ bias, const float* __restrict__ ls,
    float* __restrict__ xf, __bf16* __restrict__ out,
    __bf16* __restrict__ oq, __bf16* __restrict__ ok, __bf16* __restrict__ ov,
    int Nn)
{
    constexpr int WM = BM / 32, WN = BN / 32;
    constexpr int KS = BK / 32;
    constexpr int MT = T_ / BM;
    constexpr int nIter = K / BK;
    constexpr bool SWZ = (BK == 64);
    constexpr int RPI = 512 / BK;                 // rows per stage instr (1 KB each)
    constexpr int CL  = BK / 8;                   // 16B col slots per row
    constexpr int LPT = BM / (4 * RPI) + BN / (4 * RPI);
    static_assert(LPT == 4, "vmcnt literals assume 4 loads per tile per wave");

    __shared__ __align__(16) __bf16 sA[2][BM * BK];
    __shared__ __align__(16) __bf16 sB[2][BN * BK];

    int id = blockIdx.x;
    constexpr int nxg = (MT * NT) / 8;
    int wg = (id & 7) * nxg + (id >> 3);          // bijective XCD-chunked swizzle
    int bm = (wg / NT) * BM;                      // bm SLOW within XCD chunk
    int bn = (wg % NT) * BN;                      // bn fast -> A-panel reuse in L2
    int tid = threadIdx.x;
    int lane = tid & 63, wid = tid >> 6;
    int wm = (wid & 1) * (BM / 2), wn = (wid >> 1) * (BN / 2);
    int fm = lane & 15, fq = lane >> 4;

    f32x4 acc[WM][WN] = {};

    int lr = lane / CL, lc = lane % CL;
    int lcs = SWZ ? (lc ^ lr) : lc;               // pre-swizzled source col slot
    const __bf16* aBase = A + (size_t)(bm + wid * RPI + lr) * K + lcs * 8;
    const __bf16* bBase = Bt + (size_t)(bn + wid * RPI + lr) * K + lcs * 8;

    auto stage = [&](int buf, int kk) {
        #pragma unroll
        for (int qI = 0; qI < BM / (4 * RPI); ++qI)
            __builtin_amdgcn_global_load_lds(
                (gas_ptr)(aBase + (size_t)(qI * 4 * RPI) * K + kk),
                (las_ptr)&sA[buf][qI * 2048 + wid * 512], 16, 0, 0);
        #pragma unroll
        for (int qI = 0; qI < BN / (4 * RPI); ++qI)
            __builtin_amdgcn_global_load_lds(
                (gas_ptr)(bBase + (size_t)(qI * 4 * RPI) * K + kk),
                (las_ptr)&sB[buf][qI * 2048 + wid * 512], 16, 0, 0);
    };

    stage(0, 0);   // 4 loads in flight

    #pragma unroll
    for (int i = 0; i < nIter; ++i) {
        int cur = i & 1;
        if (i + 1 < nIter) {
            stage(cur ^ 1, (i + 1) * BK);                      // +4 loads (next tile)
            asm volatile("s_waitcnt vmcnt(4)" ::: "memory");   // tile i resident
        } else {
            asm volatile("s_waitcnt vmcnt(0)" ::: "memory");
        }
        __builtin_amdgcn_s_barrier();
        __builtin_amdgcn_sched_barrier(0);

        bf16x8 af[KS][WM], bfr[KS][WN];
        #pragma unroll
        for (int ks = 0; ks < KS; ++ks) {
            #pragma unroll
            for (int ii = 0; ii < WM; ++ii) {
                int row = wm + ii * 16 + fm;
                int c = SWZ ? (((ks * 4 + fq) ^ (row & 7)) * 8) : (ks * 32 + fq * 8);
                af[ks][ii] = *(const bf16x8*)&sA[cur][row * BK + c];
            }
            #pragma unroll
            for (int jj = 0; jj < WN; ++jj) {
                int row = wn + jj * 16 + fm;
                int c = SWZ ? (((ks * 4 + fq) ^ (row & 7)) * 8) : (ks * 32 + fq * 8);
                bfr[ks][jj] = *(const bf16x8*)&sB[cur][row * BK + c];
            }
        }
        #pragma unroll
        for (int ks = 0; ks < KS; ++ks)
            #pragma unroll
            for (int ii = 0; ii < WM; ++ii)
                #pragma unroll
                for (int jj = 0; jj < WN; ++jj)
                    acc[ii][jj] = __builtin_amdgcn_mfma_f32_16x16x32_bf16(
                        af[ks][ii], bfr[ks][jj], acc[ii][jj], 0, 0, 0);

        if (i + 1 < nIter) {
            asm volatile("s_waitcnt lgkmcnt(0)" ::: "memory");
            __builtin_amdgcn_sched_barrier(0);
            __builtin_amdgcn_s_barrier();
            __builtin_amdgcn_sched_barrier(0);
        }
    }

    // epilogue: C/D layout col=lane&15, row=(lane>>4)*4+reg
    #pragma unroll
    for (int jj = 0; jj < WN; ++jj) {
        int col = bn + wn + jj * 16 + fm;
        float bv = (MODE != 0) ? bias[col] : 0.0f;
        float lv = (MODE == 2) ? ls[col] : 0.0f;
        #pragma unroll
        for (int ii = 0; ii < WM; ++ii) {
            #pragma unroll
            for (int r = 0; r < 4; ++r) {
                int row = bm + wm + ii * 16 + fq * 4 + r;
                float v = acc[ii][jj][r];
                if (MODE == 0) {
                    if (col < 384)      oq[(size_t)row * 384 + col] = (__bf16)v;
                    else if (col < 768) ok[(size_t)row * 384 + col - 384] = (__bf16)v;
                    else {
                        int bb = row >> 8, tj = row & 255;
                        ov[((size_t)bb * 384 + (col - 768)) * 256 + tj] = (__bf16)v;
                    }
                } else if (MODE == 1) {
                    v += bv;
                    v = 0.5f * v * (1.0f + erff(v * 0.70710678118f));
                    out[(size_t)row * Nn + col] = (__bf16)v;
                } else {
                    size_t idx = (size_t)row * Nn + col;
                    xf[idx] = (v + bv) * lv + xf[idx];
                }
            }
        }
    }
}

// ---------------- fused MFMA talking-heads attention (v3, verified R4 config) ----------------
#define PAD_S 264

__global__ __launch_bounds__(384) void attn_mfma(
    const __bf16* __restrict__ q, const __bf16* __restrict__ kb,
    const __bf16* __restrict__ vT, const float* __restrict__ scale,
    const float* __restrict__ mp, const float* __restrict__ mq,
    __bf16* __restrict__ o)
{
    __shared__ __bf16 sbuf[96][PAD_S];

    int id = blockIdx.x;
    int b = (id & 7) + ((id >> 3) & 3) * 8;
    int i0 = (id >> 5) * 16;
    int tid = threadIdx.x;
    int lane = tid & 63, wid = tid >> 6;
    int fm = lane & 15, fq = lane >> 4;

    // ---- Phase 1 — QK^T: wave h computes raw S_h[16][256] ----
    int h = wid;
    bf16x8 qf[2];
    #pragma unroll
    for (int ks = 0; ks < 2; ++ks)
        qf[ks] = *(const bf16x8*)&q[(size_t)(b * 256 + i0 + fm) * 384 + h * 64 + ks * 32 + fq * 8];
    #pragma unroll 4
    for (int jt = 0; jt < 16; ++jt) {
        f32x4 a = {};
        #pragma unroll
        for (int ks = 0; ks < 2; ++ks) {
            bf16x8 bfr = *(const bf16x8*)&kb[(size_t)(b * 256 + jt * 16 + fm) * 384 + h * 64 + ks * 32 + fq * 8];
            a = __builtin_amdgcn_mfma_f32_16x16x32_bf16(qf[ks], bfr, a, 0, 0, 0);
        }
        #pragma unroll
        for (int r = 0; r < 4; ++r)
            sbuf[h * 16 + fq * 4 + r][jt * 16 + fm] = (__bf16)a[r];
    }

    float mps[36], mqs[36];
    #pragma unroll
    for (int t = 0; t < 36; ++t) { mps[t] = mp[t] * scale[t / 6]; mqs[t] = mq[t]; }

    __syncthreads();

    // ---- Phase 2 — fused premix + mask + softmax + postmix, wave per row ----
    for (int i = wid; i < 16; i += 6) {
        float sv[6][4];
        #pragma unroll
        for (int h2 = 0; h2 < 6; ++h2) {
            bf16x4 v4 = *(const bf16x4*)&sbuf[h2 * 16 + i][lane * 4];
            #pragma unroll
            for (int c = 0; c < 4; ++c) sv[h2][c] = (float)v4[c];
        }
        int drow = i0 + i;
        float pv[6][4];
        #pragma unroll
        for (int g2 = 0; g2 < 6; ++g2) {
            float t0[4];
            #pragma unroll
            for (int c = 0; c < 4; ++c) {
                float r2 = 0.f;
                #pragma unroll
                for (int h2 = 0; h2 < 6; ++h2) r2 += sv[h2][c] * mps[h2 * 6 + g2];
                t0[c] = (lane * 4 + c == drow) ? -1e30f : r2;
            }
            float m = fmaxf(fmaxf(t0[0], t0[1]), fmaxf(t0[2], t0[3]));
            #pragma unroll
            for (int off = 32; off > 0; off >>= 1) m = fmaxf(m, __shfl_xor(m, off));
            float e0 = __expf(t0[0] - m), e1 = __expf(t0[1] - m);
            float e2 = __expf(t0[2] - m), e3 = __expf(t0[3] - m);
            float s = e0 + e1 + e2 + e3;
            #pragma unroll
            for (int off = 32; off > 0; off >>= 1) s += __shfl_xor(s, off);
            float inv = 1.0f / s;
            pv[g2][0] = e0 * inv; pv[g2][1] = e1 * inv;
            pv[g2][2] = e2 * inv; pv[g2][3] = e3 * inv;
        }
        #pragma unroll
        for (int g2 = 0; g2 < 6; ++g2) {
            bf16x4 w4;
            #pragma unroll
            for (int c = 0; c < 4; ++c) {
                float r2 = 0.f;
                #pragma unroll
                for (int h2 = 0; h2 < 6; ++h2) r2 += pv[h2][c] * mqs[h2 * 6 + g2];
                w4[c] = (__bf16)r2;
            }
            *(bf16x4*)&sbuf[g2 * 16 + i][lane * 4] = w4;
        }
    }
    __syncthreads();

    // ---- Phase 3 — P @ V ----
    int gg = wid;
    f32x4 acco[4] = {};
    #pragma unroll
    for (int jc = 0; jc < 4; ++jc) {
        #pragma unroll
        for (int ks = 0; ks < 2; ++ks) {
            bf16x8 af = *(const bf16x8*)&sbuf[gg * 16 + fm][jc * 64 + ks * 32 + fq * 8];
            #pragma unroll
            for (int nt = 0; nt < 4; ++nt) {
                bf16x8 bfr = *(const bf16x8*)&vT[(size_t)(b * 384 + gg * 64 + nt * 16 + fm) * 256 + jc * 64 + ks * 32 + fq * 8];
                acco[nt] = __builtin_amdgcn_mfma_f32_16x16x32_bf16(af, bfr, acco[nt], 0, 0, 0);
            }
        }
    }
    #pragma unroll
    for (int nt = 0; nt < 4; ++nt)
        #pragma unroll
        for (int r = 0; r < 4; ++r)
            o[(size_t)(b * 256 + i0 + fq * 4 + r) * 384 + gg * 64 + nt * 16 + fm] = (__bf16)acco[nt][r];
}

extern "C" void kernel_launch(void* const* d_in, const int* in_sizes, int n_in,
                              void* d_out, int out_size, void* d_ws, size_t ws_size,
                              hipStream_t stream) {
    const float* x      = (const float*)d_in[0];
    const float* ln1_g  = (const float*)d_in[1];
    const float* ln1_b  = (const float*)d_in[2];
    const float* wq     = (const float*)d_in[3];
    const float* wkv    = (const float*)d_in[4];
    const float* scale  = (const float*)d_in[5];
    const float* mixp   = (const float*)d_in[6];
    const float* mixq   = (const float*)d_in[7];
    const float* wo     = (const float*)d_in[8];
    const float* bo     = (const float*)d_in[9];
    const float* ls1    = (const float*)d_in[10];
    const float* ln2_g  = (const float*)d_in[11];
    const float* ln2_b  = (const float*)d_in[12];
    const float* w1     = (const float*)d_in[13];
    const float* b1     = (const float*)d_in[14];
    const float* w2     = (const float*)d_in[15];
    const float* b2     = (const float*)d_in[16];
    const float* ls2    = (const float*)d_in[17];

    char* ws = (char*)d_ws;
    float*  xf = (float*)ws;                      ws += (size_t)T_ * DIM_ * 4;
    __bf16* y  = (__bf16*)ws;                     ws += (size_t)T_ * DIM_ * 2;
    __bf16* q  = (__bf16*)ws;                     ws += (size_t)T_ * DIM_ * 2;
    __bf16* kb = (__bf16*)ws;                     ws += (size_t)T_ * DIM_ * 2;
    __bf16* vT = (__bf16*)ws;                     ws += (size_t)T_ * DIM_ * 2;
    __bf16* o  = (__bf16*)ws;                     ws += (size_t)T_ * DIM_ * 2;
    __bf16* wbuf = (__bf16*)ws;                   ws += (size_t)WBUF_ELEMS * DEPTH_ * 2;
    __bf16* h  = q;   // MLP hidden [T][1536] overlays q+kb+vT+o (25.2MB, exact fit)

    size_t nBytes = (size_t)T_ * DIM_ * sizeof(float);
    hipMemcpyAsync(xf, x, nBytes, hipMemcpyDeviceToDevice, stream);

    // all-layer weight conversion up front (one dispatch)
    convert_w_all<<<432 * DEPTH_, 256, 0, stream>>>(wq, wkv, wo, w1, w2, wbuf);

    for (int l = 0; l < DEPTH_; ++l) {
        __bf16* wl = wbuf + (size_t)l * WBUF_ELEMS;

        ln1w<<<T_, 64, 0, stream>>>(xf, ln1_g + (size_t)l * DIM_, ln1_b + (size_t)l * DIM_, y);

        // QKV: 64 M-tiles x 9 N-tiles = 576 blocks
        gemmt<0, 384, 128, 128, 32, 9><<<576, 256, 0, stream>>>(
            y, wl + WQKV_OFF, nullptr, nullptr, nullptr, nullptr,
            q, kb, vT, 1152);

        // attention: 512 blocks, batch pinned to XCD
        attn_mfma<<<512, 384, 0, stream>>>(
            q, kb, vT, scale + (size_t)l * H_,
            mixp + (size_t)l * H_ * H_, mixq + (size_t)l * H_ * H_, o);

        // O-proj: 128 x 6 = 768 blocks (64x64, BK=64 swizzled)
        gemmt<2, 384, 64, 64, 64, 6><<<768, 256, 0, stream>>>(
            o, wl + WO_OFF, bo + (size_t)l * DIM_, ls1 + (size_t)l * DIM_,
            xf, nullptr, nullptr, nullptr, nullptr, DIM_);

        ln1w<<<T_, 64, 0, stream>>>(xf, ln2_g + (size_t)l * DIM_, ln2_b + (size_t)l * DIM_, y);

        // MLP1: 64 x 12 = 768 blocks
        gemmt<1, 384, 128, 128, 32, 12><<<768, 256, 0, stream>>>(
            y, wl + W1_OFF, b1 + (size_t)l * MLP_, nullptr,
            nullptr, h, nullptr, nullptr, nullptr, MLP_);

        // MLP2: 128 x 6 = 768 blocks (64x64, BK=64 swizzled, K=1536)
        gemmt<2, 1536, 64, 64, 64, 6><<<768, 256, 0, stream>>>(
            h, wl + W2_OFF, b2 + (size_t)l * DIM_, ls2 + (size_t)l * DIM_,
            xf, nullptr, nullptr, nullptr, nullptr, DIM_);
    }

    hipMemcpyAsync(d_out, xf, nBytes, hipMemcpyDeviceToDevice, stream);
}